// Round 3
// baseline (521.358 us; speedup 1.0000x reference)
//
#include <hip/hip_runtime.h>

// LocEncoder fused, dst-binned (atomic-free epilogue).
//
//  k0: memset cnt[100k] = 0
//  k1 fill:  p = atomicAdd(cnt[dst]); slot[dst*64+p] = src   (1.6M atomics
//            total vs ~51M per-dim atomicMax in the edge-centric version)
//  k2 node:  wave per node; 16-edge MFMA tiles; register max over rows;
//            one coalesced store per node. relu + empty-segment-0 via 0-init
//            of the register max.
//
// GEMM2's K order is permuted (k' = n*4 + t) so the C->A layout transform is
// vectorized (ds_write_b64 / ds_read_b128); W2 rows permuted identically.

#define N_NODES 100000
#define N_EDGES 1600000
#define CAP 64           // max degree capacity; Poisson(16) max ~45 << 64
#define WPB 4

typedef short short8  __attribute__((ext_vector_type(8)));
typedef short short4v __attribute__((ext_vector_type(4)));
typedef float float4v __attribute__((ext_vector_type(4)));

__device__ inline short f2bf(float f) {  // fp32 -> bf16 RNE
    union { float f; unsigned u; } v; v.f = f;
    unsigned u = v.u;
    u += 0x7fffu + ((u >> 16) & 1u);
    return (short)(u >> 16);
}

__global__ __launch_bounds__(256) void fill_kernel(
    const int* __restrict__ ei, int* __restrict__ cnt, int* __restrict__ slot)
{
    int e = blockIdx.x * blockDim.x + threadIdx.x;
    const int stride = gridDim.x * blockDim.x;
    for (; e < N_EDGES; e += stride) {
        const int src = ei[e];
        const int dst = ei[N_EDGES + e];
        const int p = atomicAdd(&cnt[dst], 1);
        if (p < CAP) slot[dst * CAP + p] = src;
    }
}

__global__ __launch_bounds__(256) void node_kernel(
    const float* __restrict__ x,     // [N,13]
    const float* __restrict__ pos,   // [N,3]
    const float* __restrict__ W1,    // [16,64]
    const float* __restrict__ b1,    // [64]
    const float* __restrict__ W2,    // [64,64]
    const float* __restrict__ b2,    // [64]
    const int*   __restrict__ cnt,   // [N]
    const int*   __restrict__ slot,  // [N,CAP]
    float*       __restrict__ out)   // [N,64]
{
    __shared__ alignas(16) short h1s[WPB][16 * 72];  // 144-B rows: 2-way bank = free

    const int lane = threadIdx.x & 63;
    const int wv   = threadIdx.x >> 6;
    const int q    = lane >> 4;
    const int n    = lane & 15;

    // ---- weight fragments (amortized over ~12-25 nodes/wave) ----
    short8 w1f[4];
    for (int t = 0; t < 4; ++t)
        for (int j = 0; j < 8; ++j) {
            int k = q * 8 + j;
            w1f[t][j] = (k < 16) ? f2bf(W1[k * 64 + (n + 16 * t)]) : (short)0;
        }
    short8 w2f[2][4];
    for (int s = 0; s < 2; ++s)
        for (int t = 0; t < 4; ++t)
            for (int j = 0; j < 8; ++j) {
                int kk = s * 32 + q * 8 + j;
                int ko = (kk >> 2) + 16 * (kk & 3);  // un-permute
                w2f[s][t][j] = f2bf(W2[ko * 64 + (n + 16 * t)]);
            }
    float b1c[4], b2c[4];
    for (int t = 0; t < 4; ++t) { b1c[t] = b1[n + 16 * t]; b2c[t] = b2[n + 16 * t]; }

    short* myLds = &h1s[wv][0];
    const int waveId = blockIdx.x * WPB + wv;
    const int nwave  = gridDim.x * WPB;

    for (int nd = waveId; nd < N_NODES; nd += nwave) {
        const int node = __builtin_amdgcn_readfirstlane(nd);
        int deg = cnt[node];
        deg = deg < CAP ? deg : CAP;

        float pd[3];
#pragma unroll
        for (int c = 0; c < 3; ++c) pd[c] = pos[node * 3 + c];

        float vmax[4] = {0.f, 0.f, 0.f, 0.f};  // 0-init == final relu + empty=0

        for (int base = 0; base < deg; base += 16) {
            const int rows = (deg - base) < 16 ? (deg - base) : 16;
            const int src  = (n < rows) ? slot[node * CAP + base + n] : 0;

            // A1: A[m = edge n][k = q*8+j], k in [16,32) zero
            short8 a1 = {0, 0, 0, 0, 0, 0, 0, 0};
            if (q == 0) {
#pragma unroll
                for (int j = 0; j < 8; ++j) a1[j] = f2bf(x[src * 13 + j]);
            } else if (q == 1) {
#pragma unroll
                for (int j = 0; j < 5; ++j) a1[j] = f2bf(x[src * 13 + 8 + j]);
#pragma unroll
                for (int c = 0; c < 3; ++c)
                    a1[5 + c] = f2bf(pos[src * 3 + c] - pd[c]);
            }

            float4v c1[4];
#pragma unroll
            for (int t = 0; t < 4; ++t)
                c1[t] = __builtin_amdgcn_mfma_f32_16x16x32_bf16(
                    a1, w1f[t], (float4v){0.f, 0.f, 0.f, 0.f}, 0, 0, 0);

            // bias+relu, pack to LDS at permuted k' = n*4 + t
#pragma unroll
            for (int r = 0; r < 4; ++r) {
                short4v pk;
#pragma unroll
                for (int t = 0; t < 4; ++t)
                    pk[t] = f2bf(fmaxf(c1[t][r] + b1c[t], 0.f));
                *(short4v*)(myLds + (q * 4 + r) * 72 + n * 4) = pk;
            }

            const short8 a2s0 = *(short8*)(myLds + n * 72 + q * 8);
            const short8 a2s1 = *(short8*)(myLds + n * 72 + 32 + q * 8);

            float4v c2[4];
#pragma unroll
            for (int t = 0; t < 4; ++t) {
                c2[t] = __builtin_amdgcn_mfma_f32_16x16x32_bf16(
                    a2s0, w2f[0][t], (float4v){0.f, 0.f, 0.f, 0.f}, 0, 0, 0);
                c2[t] = __builtin_amdgcn_mfma_f32_16x16x32_bf16(
                    a2s1, w2f[1][t], c2[t], 0, 0, 0);
            }

            // masked max over valid rows, in registers
#pragma unroll
            for (int r = 0; r < 4; ++r) {
                const int row = q * 4 + r;
#pragma unroll
                for (int t = 0; t < 4; ++t) {
                    const float v = c2[t][r] + b2c[t];
                    if (row < rows) vmax[t] = fmaxf(vmax[t], v);
                }
            }
        }

        // cross-quad max (rows live across quads)
#pragma unroll
        for (int t = 0; t < 4; ++t) {
            vmax[t] = fmaxf(vmax[t], __shfl_xor(vmax[t], 16));
            vmax[t] = fmaxf(vmax[t], __shfl_xor(vmax[t], 32));
        }
        // lane (q,n) -> dim n+16q == lane: fully coalesced store
        float v = vmax[0];
        v = (q == 1) ? vmax[1] : v;
        v = (q == 2) ? vmax[2] : v;
        v = (q == 3) ? vmax[3] : v;
        out[node * 64 + lane] = v;
    }
}

extern "C" void kernel_launch(void* const* d_in, const int* in_sizes, int n_in,
                              void* d_out, int out_size, void* d_ws, size_t ws_size,
                              hipStream_t stream) {
    const float* x   = (const float*)d_in[0];
    const float* pos = (const float*)d_in[1];
    const float* W1  = (const float*)d_in[2];
    const float* b1  = (const float*)d_in[3];
    const float* W2  = (const float*)d_in[4];
    const float* b2  = (const float*)d_in[5];
    const int*   ei  = (const int*)d_in[6];

    int* cnt  = (int*)d_ws;                       // 100k ints
    int* slot = (int*)((char*)d_ws + 400128);     // [N, CAP] ints, 25.6 MB

    hipMemsetAsync(cnt, 0, N_NODES * sizeof(int), stream);
    fill_kernel<<<3200, 256, 0, stream>>>(ei, cnt, slot);
    node_kernel<<<2048, 256, 0, stream>>>(x, pos, W1, b1, W2, b2,
                                          cnt, slot, (float*)d_out);
}

// Round 4
// 311.859 us; speedup vs baseline: 1.6718x; 1.6718x over previous
//
#include <hip/hip_runtime.h>
#include <hip/hip_bf16.h>

// LocEncoder fused, dst-binned (atomic-free epilogue), round 4:
// fix scratch-demotion of weight fragments (all preload loops fully
// unrolled -> register-resident), packed bf16 converts, batched-atomic fill.
//
//  k0: memset cnt[100k] = 0
//  k1 fill:  4 edges/thread, 4 atomicAdds in flight, slot[dst*64+p] = src
//  k2 node:  wave per node; 16-edge MFMA tiles; register max over rows;
//            one coalesced store per node. relu + empty-segment-0 via 0-init.
//
// GEMM2's K order is permuted (k' = n*4 + t) so the C->A layout transform is
// vectorized (ds_write_b64 / ds_read_b128); W2 rows permuted identically.

#define N_NODES 100000
#define N_EDGES 1600000
#define CAP 64           // max degree capacity; Poisson(16) max ~45 << 64
#define WPB 4

typedef short short8  __attribute__((ext_vector_type(8)));
typedef short short4v __attribute__((ext_vector_type(4)));
typedef float float4v __attribute__((ext_vector_type(4)));

__device__ inline short f2bf(float f) {  // scalar fp32->bf16 RNE (preload only)
    union { float f; unsigned u; } v; v.f = f;
    unsigned u = v.u;
    u += 0x7fffu + ((u >> 16) & 1u);
    return (short)(u >> 16);
}

__device__ inline short2 f2bf2(float a, float b) {  // v_cvt_pk_bf16_f32
    __hip_bfloat162 h = __float22bfloat162_rn(make_float2(a, b));
    return *(short2*)&h;
}

__global__ __launch_bounds__(256) void fill_kernel(
    const int* __restrict__ ei, int* __restrict__ cnt, int* __restrict__ slot)
{
    const int t  = blockIdx.x * blockDim.x + threadIdx.x;
    const int e0 = t * 4;
    if (e0 >= N_EDGES) return;   // N_EDGES % 4 == 0: no partial tail
    const int4 s4 = *(const int4*)(ei + e0);
    const int4 d4 = *(const int4*)(ei + N_EDGES + e0);
    // 4 independent atomics in flight, then the dependent stores
    const int p0 = atomicAdd(&cnt[d4.x], 1);
    const int p1 = atomicAdd(&cnt[d4.y], 1);
    const int p2 = atomicAdd(&cnt[d4.z], 1);
    const int p3 = atomicAdd(&cnt[d4.w], 1);
    if (p0 < CAP) slot[d4.x * CAP + p0] = s4.x;
    if (p1 < CAP) slot[d4.y * CAP + p1] = s4.y;
    if (p2 < CAP) slot[d4.z * CAP + p2] = s4.z;
    if (p3 < CAP) slot[d4.w * CAP + p3] = s4.w;
}

__global__ __launch_bounds__(256, 3) void node_kernel(
    const float* __restrict__ x,     // [N,13]
    const float* __restrict__ pos,   // [N,3]
    const float* __restrict__ W1,    // [16,64]
    const float* __restrict__ b1,    // [64]
    const float* __restrict__ W2,    // [64,64]
    const float* __restrict__ b2,    // [64]
    const int*   __restrict__ cnt,   // [N]
    const int*   __restrict__ slot,  // [N,CAP]
    float*       __restrict__ out)   // [N,64]
{
    __shared__ alignas(16) short h1s[WPB][16 * 72];  // 144-B rows: 2-way bank = free

    const int lane = threadIdx.x & 63;
    const int wv   = threadIdx.x >> 6;
    const int q    = lane >> 4;
    const int n    = lane & 15;

    // ---- weight fragments: FULLY UNROLLED so they stay in VGPRs ----
    short8 w1f[4];
#pragma unroll
    for (int t = 0; t < 4; ++t)
#pragma unroll
        for (int j = 0; j < 8; ++j) {
            const int k = q * 8 + j;
            w1f[t][j] = (k < 16) ? f2bf(W1[k * 64 + (n + 16 * t)]) : (short)0;
        }
    short8 w2f[2][4];
#pragma unroll
    for (int s = 0; s < 2; ++s)
#pragma unroll
        for (int t = 0; t < 4; ++t)
#pragma unroll
            for (int j = 0; j < 8; ++j) {
                const int kk = s * 32 + q * 8 + j;
                const int ko = (kk >> 2) + 16 * (kk & 3);  // un-permute
                w2f[s][t][j] = f2bf(W2[ko * 64 + (n + 16 * t)]);
            }
    float b1c[4], b2c[4];
#pragma unroll
    for (int t = 0; t < 4; ++t) { b1c[t] = b1[n + 16 * t]; b2c[t] = b2[n + 16 * t]; }

    short* myLds = &h1s[wv][0];
    const int waveId = blockIdx.x * WPB + wv;
    const int nwave  = gridDim.x * WPB;

    for (int nd = waveId; nd < N_NODES; nd += nwave) {
        const int node = __builtin_amdgcn_readfirstlane(nd);
        int deg = cnt[node];
        deg = deg < CAP ? deg : CAP;

        float pd[3];
#pragma unroll
        for (int c = 0; c < 3; ++c) pd[c] = pos[node * 3 + c];

        float vmax[4] = {0.f, 0.f, 0.f, 0.f};  // 0-init == final relu + empty=0

        for (int base = 0; base < deg; base += 16) {
            const int rows = (deg - base) < 16 ? (deg - base) : 16;
            const int src  = (n < rows) ? slot[node * CAP + base + n] : 0;

            // A1: A[m = edge n][k = q*8+j], k in [16,32) zero
            union { short8 v; short2 h[4]; } a1;
            a1.v = (short8){0, 0, 0, 0, 0, 0, 0, 0};
            if (q == 0) {
                float f[8];
#pragma unroll
                for (int j = 0; j < 8; ++j) f[j] = x[src * 13 + j];
#pragma unroll
                for (int j = 0; j < 4; ++j) a1.h[j] = f2bf2(f[2 * j], f[2 * j + 1]);
            } else if (q == 1) {
                float f[8];
#pragma unroll
                for (int j = 0; j < 5; ++j) f[j] = x[src * 13 + 8 + j];
#pragma unroll
                for (int c = 0; c < 3; ++c) f[5 + c] = pos[src * 3 + c] - pd[c];
#pragma unroll
                for (int j = 0; j < 4; ++j) a1.h[j] = f2bf2(f[2 * j], f[2 * j + 1]);
            }

            float4v c1[4];
#pragma unroll
            for (int t = 0; t < 4; ++t)
                c1[t] = __builtin_amdgcn_mfma_f32_16x16x32_bf16(
                    a1.v, w1f[t], (float4v){0.f, 0.f, 0.f, 0.f}, 0, 0, 0);

            // bias+relu, packed cvt, LDS at permuted k' = n*4 + t
#pragma unroll
            for (int r = 0; r < 4; ++r) {
                union { short4v v; short2 h[2]; } pk;
                pk.h[0] = f2bf2(fmaxf(c1[0][r] + b1c[0], 0.f),
                                fmaxf(c1[1][r] + b1c[1], 0.f));
                pk.h[1] = f2bf2(fmaxf(c1[2][r] + b1c[2], 0.f),
                                fmaxf(c1[3][r] + b1c[3], 0.f));
                *(short4v*)(myLds + (q * 4 + r) * 72 + n * 4) = pk.v;
            }

            const short8 a2s0 = *(short8*)(myLds + n * 72 + q * 8);
            const short8 a2s1 = *(short8*)(myLds + n * 72 + 32 + q * 8);

            float4v c2[4];
#pragma unroll
            for (int t = 0; t < 4; ++t) {
                c2[t] = __builtin_amdgcn_mfma_f32_16x16x32_bf16(
                    a2s0, w2f[0][t], (float4v){0.f, 0.f, 0.f, 0.f}, 0, 0, 0);
                c2[t] = __builtin_amdgcn_mfma_f32_16x16x32_bf16(
                    a2s1, w2f[1][t], c2[t], 0, 0, 0);
            }

            // masked max over valid rows, in registers
#pragma unroll
            for (int r = 0; r < 4; ++r) {
                const int row = q * 4 + r;
#pragma unroll
                for (int t = 0; t < 4; ++t) {
                    const float v = c2[t][r] + b2c[t];
                    if (row < rows) vmax[t] = fmaxf(vmax[t], v);
                }
            }
        }

        // cross-quad max (rows live across quads)
#pragma unroll
        for (int t = 0; t < 4; ++t) {
            vmax[t] = fmaxf(vmax[t], __shfl_xor(vmax[t], 16));
            vmax[t] = fmaxf(vmax[t], __shfl_xor(vmax[t], 32));
        }
        // lane (q,n) -> dim n+16q == lane: fully coalesced store
        float v = vmax[0];
        v = (q == 1) ? vmax[1] : v;
        v = (q == 2) ? vmax[2] : v;
        v = (q == 3) ? vmax[3] : v;
        out[node * 64 + lane] = v;
    }
}

extern "C" void kernel_launch(void* const* d_in, const int* in_sizes, int n_in,
                              void* d_out, int out_size, void* d_ws, size_t ws_size,
                              hipStream_t stream) {
    const float* x   = (const float*)d_in[0];
    const float* pos = (const float*)d_in[1];
    const float* W1  = (const float*)d_in[2];
    const float* b1  = (const float*)d_in[3];
    const float* W2  = (const float*)d_in[4];
    const float* b2  = (const float*)d_in[5];
    const int*   ei  = (const int*)d_in[6];

    int* cnt  = (int*)d_ws;                       // 100k ints
    int* slot = (int*)((char*)d_ws + 400128);     // [N, CAP] ints, 25.6 MB

    hipMemsetAsync(cnt, 0, N_NODES * sizeof(int), stream);
    fill_kernel<<<(N_EDGES / 4 + 255) / 256, 256, 0, stream>>>(ei, cnt, slot);
    node_kernel<<<2048, 256, 0, stream>>>(x, pos, W1, b1, W2, b2,
                                          cnt, slot, (float*)d_out);
}